// Round 8
// baseline (213.484 us; speedup 1.0000x reference)
//
#include <hip/hip_runtime.h>
#include <hip/hip_bf16.h>

// ---------- problem constants ----------
#define BATCH   2
#define SEQ     2048
#define DMODEL  1024
#define NHEADS  16
#define DHEAD   64
#define MROWS   (BATCH*SEQ)     // 4096
#define NBH     (BATCH*NHEADS)  // 32

typedef float  f32x4  __attribute__((ext_vector_type(4)));
typedef short  s16x4  __attribute__((ext_vector_type(4)));
typedef short  s16x8  __attribute__((ext_vector_type(8)));
typedef __bf16 bf16x8 __attribute__((ext_vector_type(8)));

__device__ __forceinline__ short f2bf(float f) {
  union { float f; unsigned u; } v; v.f = f;
  return (short)((v.u + 0x7fffu + ((v.u >> 16) & 1u)) >> 16);  // RNE
}
__device__ __forceinline__ float bf2f(short s) {
  union { unsigned u; float f; } v; v.u = ((unsigned)(unsigned short)s) << 16;
  return v.f;
}

// ---------- fused prep: z<4 -> W transpose+bf16; z>=4 -> x fp32->bf16 -------
__global__ void prep_fused(const float* __restrict__ x, short* __restrict__ xb,
                           const float* __restrict__ Wq, const float* __restrict__ Wk,
                           const float* __restrict__ Wv, const float* __restrict__ Wo,
                           short* __restrict__ WtQKV, short* __restrict__ WtO) {
  __shared__ float t[32][33];
  int z = blockIdx.z;
  int tx = threadIdx.x, ty = threadIdx.y;           // block (32,8)
  if (z >= 4) {                                     // convert x chunk
    int blk = (z - 4) * 1024 + blockIdx.y * 32 + blockIdx.x;
    int i = (blk * 256 + ty * 32 + tx) * 4;
    float4 v = *(const float4*)(x + i);
    s16x4 o = { f2bf(v.x), f2bf(v.y), f2bf(v.z), f2bf(v.w) };
    *(s16x4*)(xb + i) = o;
    return;
  }
  const float* W; short* Wt;
  if      (z == 0) { W = Wq; Wt = WtQKV; }
  else if (z == 1) { W = Wk; Wt = WtQKV + (1u << 20); }
  else if (z == 2) { W = Wv; Wt = WtQKV + (2u << 20); }
  else             { W = Wo; Wt = WtO; }
  int n0 = blockIdx.x * 32, k0 = blockIdx.y * 32;
  #pragma unroll
  for (int i = 0; i < 32; i += 8) t[ty + i][tx] = W[(k0 + ty + i) * DMODEL + n0 + tx];
  __syncthreads();
  #pragma unroll
  for (int i = 0; i < 32; i += 8) Wt[(n0 + ty + i) * DMODEL + k0 + tx] = f2bf(t[tx][ty + i]);
}

// ---------- bf16 GEMM, m97 structure: C = A[M][K] * Wt[N][K]^T ----------
template<int MT, int NT, int EPI>
__global__ __launch_bounds__(256) void gemm_bf16(
    const short* __restrict__ A, const short* __restrict__ Bt,
    const float* __restrict__ bq, const float* __restrict__ bk, const float* __restrict__ bv,
    short* __restrict__ qb, short* __restrict__ kb, short* __restrict__ vt,
    float* __restrict__ out)
{
  constexpr int K = DMODEL, BK = 32;
  constexpr int WM = MT / 2, WN = NT / 2;
  constexpr int TM = WM / 16, TN = WN / 16;
  constexpr int CA = MT * BK / 512;
  constexpr int CB = NT * BK / 512;
  constexpr int TP = 136;                            // epilogue tile pitch (shorts)
  constexpr int SME = (EPI == 0) ? 128 * TP : (MT * BK + NT * BK);
  __shared__ short smem[SME];
  short* la = smem;
  short* lb = smem + MT * BK;
  const int tid = threadIdx.x;
  const int wave = tid >> 6, lane = tid & 63;
  const int quad = lane >> 4, l16 = lane & 15;
  const int wr = wave >> 1, wc = wave & 1;
  const int m0 = blockIdx.y * MT, n0 = blockIdx.x * NT;
  const int arow = lane >> 2, acol = (lane & 3) * 8;

  f32x4 acc[TM][TN] = {};

  for (int k0 = 0; k0 < K; k0 += BK) {
    for (int c = wave; c < CA; c += 4) {
      const short* gp = A + (m0 + c * 16 + arow) * K + k0 + acol;
      __builtin_amdgcn_global_load_lds((__attribute__((address_space(1))) void*)gp,
                                       (__attribute__((address_space(3))) void*)(la + c * 512),
                                       16, 0, 0);
    }
    for (int c = wave; c < CB; c += 4) {
      const short* gp = Bt + (n0 + c * 16 + arow) * K + k0 + acol;
      __builtin_amdgcn_global_load_lds((__attribute__((address_space(1))) void*)gp,
                                       (__attribute__((address_space(3))) void*)(lb + c * 512),
                                       16, 0, 0);
    }
    __syncthreads();
    bf16x8 af[TM], bfr[TN];
    #pragma unroll
    for (int i = 0; i < TM; ++i)
      af[i] = *(const bf16x8*)&la[(wr * WM + i * 16 + l16) * BK + quad * 8];
    #pragma unroll
    for (int j = 0; j < TN; ++j)
      bfr[j] = *(const bf16x8*)&lb[(wc * WN + j * 16 + l16) * BK + quad * 8];
    #pragma unroll
    for (int i = 0; i < TM; ++i)
      #pragma unroll
      for (int j = 0; j < TN; ++j)
        acc[i][j] = __builtin_amdgcn_mfma_f32_16x16x32_bf16(af[i], bfr[j], acc[i][j], 0, 0, 0);
    __syncthreads();
  }

  if constexpr (EPI == 0) {
    const bool isV = (n0 >= 2 * DMODEL);
    const float* bias; int nbase; float scl;
    // Q scale folds 1/sqrt(Dh) AND log2(e) so attention uses exp2 directly.
    if (n0 < DMODEL)          { bias = bq; nbase = 0;          scl = 0.125f * 1.44269504089f; }
    else if (n0 < 2 * DMODEL) { bias = bk; nbase = DMODEL;     scl = 1.f; }
    else                      { bias = bv; nbase = 2 * DMODEL; scl = 1.f; }
    #pragma unroll
    for (int j = 0; j < TN; ++j) {
      int coll = wc * WN + j * 16 + l16;
      float bias_v = bias[n0 - nbase + coll];
      #pragma unroll
      for (int i = 0; i < TM; ++i) {
        int rowl = wr * WM + i * 16 + quad * 4;
        #pragma unroll
        for (int r = 0; r < 4; ++r) {
          short v = f2bf((acc[i][j][r] + bias_v) * scl);
          if (isV) smem[coll * TP + rowl + r] = v;   // transposed for V
          else     smem[(rowl + r) * TP + coll] = v;
        }
      }
    }
    __syncthreads();
    const int b = m0 >> 11, s0 = m0 & (SEQ - 1);
    const int rseg = tid & 15, rrow = tid >> 4;
    if (!isV) {
      short* dst = (n0 < DMODEL) ? qb : kb;
      #pragma unroll
      for (int it = 0; it < 8; ++it) {
        int row = it * 16 + rrow;
        int colg = (n0 - nbase) + rseg * 8;
        int h = colg >> 6, d = colg & 63;
        s16x8 v = *(const s16x8*)&smem[row * TP + rseg * 8];
        *(s16x8*)(dst + ((b * NHEADS + h) * SEQ + s0 + row) * DHEAD + d) = v;
      }
    } else {
      #pragma unroll
      for (int it = 0; it < 8; ++it) {
        int drow = it * 16 + rrow;
        int colg = (n0 - nbase) + drow;
        int h = colg >> 6, d = colg & 63;
        s16x8 v = *(const s16x8*)&smem[drow * TP + rseg * 8];
        *(s16x8*)(vt + ((b * NHEADS + h) * DHEAD + d) * SEQ + s0 + rseg * 8) = v;
      }
    }
  } else {
    #pragma unroll
    for (int i = 0; i < TM; ++i)
      #pragma unroll
      for (int r = 0; r < 4; ++r) {
        int mrow = m0 + wr * WM + i * 16 + quad * 4 + r;
        #pragma unroll
        for (int j = 0; j < TN; ++j)
          out[mrow * DMODEL + n0 + wc * WN + j * 16 + l16] = acc[i][j][r];
      }
    (void)bq; (void)bk; (void)bv; (void)qb; (void)kb; (void)vt;
  }
}

// ================= flash attention v7: 4 frags/wave x quarter-T split =========
// R7 post-mortem: 4-frag LDS reuse helped; residual is the serial per-tile
// chain (QK MFMA -> exp2 -> pack -> PV) exposed at only 2 blocks/CU (grid 512
// capped occupancy; VGPR=76/LDS=32KB allow 4). v7 combines R6+R7: keep 4
// frags/wave AND split each (qg,bh) into FOUR blocks (chunks c == q mod 4;
// partials merge by pure addition - softmax is unnormalized exp2). Grid 1024
// = 4 blocks/CU -> 4 independent barrier pipelines hide the chains.

__global__ __launch_bounds__(256, 4) void attn_k(
    const short* __restrict__ qbp, const short* __restrict__ kbp,
    const short* __restrict__ vtb, short* __restrict__ oP, float* __restrict__ lP)
{
  __shared__ short kls[2][4096];                    // 2 x 8KB
  __shared__ short vls[2][4096];                    // 2 x 8KB
  const int tid = threadIdx.x, wave = tid >> 6, lane = tid & 63;
  const int quad = lane >> 4, l16 = lane & 15;
  const int qtr = blockIdx.x & 3;                   // T-quarter 0..3
  const int bh = (blockIdx.x >> 2) & 31;
  const int qg = blockIdx.x >> 7;                   // 0..7, long (qg=0) first
  const int qt1 = qg * 8 + wave * 2;                // 0..62 even
  // fragment rows (ascending): pairs (qt1,127-qt1),(qt1+1,126-qt1)
  const int mF[4] = { qt1 * 16, (qt1 + 1) * 16, (126 - qt1) * 16, (127 - qt1) * 16 };
  const int nch = (127 - 8 * qg) / 4 + 1;          // block-uniform chunk count
  const short* Q  = qbp + bh * SEQ * DHEAD;
  const short* Kp = kbp + bh * SEQ * DHEAD;
  const short* Vt = vtb + bh * DHEAD * SEQ;

  bf16x8 qf[4][2];
  #pragma unroll
  for (int f = 0; f < 4; ++f) {
    qf[f][0] = *(const bf16x8*)&Q[(mF[f] + l16) * DHEAD + quad * 8];
    qf[f][1] = *(const bf16x8*)&Q[(mF[f] + l16) * DHEAD + 32 + quad * 8];
  }

  float lF[4] = {};
  f32x4 oF[4][4] = {};

  const int vdl = lane >> 3, vsl = lane & 7;        // V staging lane split

  auto stage = [&](int buf, int t0) {
    #pragma unroll
    for (int j = 0; j < 2; ++j) {
      int g = j * 4 + wave;                         // K ch-group 0..7
      const short* gp = Kp + (t0 + lane) * DHEAD + g * 8;
      __builtin_amdgcn_global_load_lds((__attribute__((address_space(1))) void*)gp,
                                       (__attribute__((address_space(3))) void*)&kls[buf][g * 512],
                                       16, 0, 0);
    }
    #pragma unroll
    for (int j = 0; j < 2; ++j) {
      int gd = j * 4 + wave;                        // V d-block 0..7
      const short* gp = Vt + (gd * 8 + vdl) * SEQ + t0 + ((vsl ^ vdl) * 8);
      __builtin_amdgcn_global_load_lds((__attribute__((address_space(1))) void*)gp,
                                       (__attribute__((address_space(3))) void*)&vls[buf][gd * 512],
                                       16, 0, 0);
    }
  };

  stage(0, qtr * 64);
  for (int c = qtr; c < nch; c += 4) {
    __syncthreads();                                // drains stage(c); waves synced
    if (c + 4 < nch) stage(((c >> 2) + 1) & 1, (c + 4) * 64);
    const int t0 = c * 64;
    const int buf = (c >> 2) & 1;
    #pragma unroll
    for (int t = 0; t < 4; ++t) {
      const int tb = t0 + t * 16;
      if (tb <= mF[3]) {                            // any fragment live (wave-uniform)
        bf16x8 kf0 = *(const bf16x8*)&kls[buf][((0 + quad) * 64 + t * 16 + l16) * 8];
        bf16x8 kf1 = *(const bf16x8*)&kls[buf][((4 + quad) * 64 + t * 16 + l16) * 8];
        s16x4 vf[4];
        {
          int gsw = ((t * 2 + (quad >> 1)) ^ (l16 & 7));
          #pragma unroll
          for (int dt = 0; dt < 4; ++dt)
            vf[dt] = *(const s16x4*)&vls[buf][((dt * 16 + l16) * 8 + gsw) * 8 + (quad & 1) * 4];
        }
        #pragma unroll
        for (int f = 0; f < 4; ++f) {
          if (tb <= mF[f]) {                        // wave-uniform
            f32x4 a = {};
            a = __builtin_amdgcn_mfma_f32_16x16x32_bf16(kf0, qf[f][0], a, 0, 0, 0);
            a = __builtin_amdgcn_mfma_f32_16x16x32_bf16(kf1, qf[f][1], a, 0, 0, 0);
            if (tb == mF[f]) {                      // diagonal: mask t > m
              #pragma unroll
              for (int r = 0; r < 4; ++r)
                if (quad * 4 + r > l16) a[r] = -1e30f;
            }
            f32x4 p;
            #pragma unroll
            for (int r = 0; r < 4; ++r) p[r] = __builtin_amdgcn_exp2f(a[r]);
            lF[f] += (p[0] + p[1]) + (p[2] + p[3]);
            __hip_bfloat162 c01 = __float22bfloat162_rn(float2{p[0], p[1]});
            __hip_bfloat162 c23 = __float22bfloat162_rn(float2{p[2], p[3]});
            union { unsigned u[2]; s16x4 s; } pu;
            pu.u[0] = *(unsigned*)&c01; pu.u[1] = *(unsigned*)&c23;
            #pragma unroll
            for (int dt = 0; dt < 4; ++dt)
              oF[f][dt] = __builtin_amdgcn_mfma_f32_16x16x16bf16_1k(pu.s, vf[dt], oF[f][dt], 0, 0, 0);
          }
        }
      }
    }
  }

  // reduce l across quads; store partials [qtr][bh][s][64]
  float* lD = lP + (qtr * NBH + bh) * SEQ;
  short* oD = oP + ((qtr * NBH + bh) * SEQ) * DHEAD;
  #pragma unroll
  for (int f = 0; f < 4; ++f) {
    float l = lF[f];
    l += __shfl_xor(l, 16, 64); l += __shfl_xor(l, 32, 64);
    if (quad == 0) lD[mF[f] + l16] = l;
    #pragma unroll
    for (int r = 0; r < 4; ++r) {
      int s = mF[f] + quad * 4 + r;
      #pragma unroll
      for (int dt = 0; dt < 4; ++dt)
        oD[s * DHEAD + dt * 16 + l16] = f2bf(oF[f][dt][r]);
    }
  }
}

// ---------- merge quarters: ob = sum(oQ) / sum(lQ), bf16 [b][s][h*64+d] ------
__global__ void attn_merge(const short* __restrict__ oP, const float* __restrict__ lP,
                           short* __restrict__ ob) {
  int idx = blockIdx.x * 256 + threadIdx.x;         // one thread = 8 outputs
  int d8 = idx & 7, s = (idx >> 3) & (SEQ - 1), bh = idx >> 14;
  float acc[8] = {};
  float lsum = 0.f;
  #pragma unroll
  for (int q = 0; q < 4; ++q) {
    s16x8 e = *(const s16x8*)&oP[((q * NBH + bh) * SEQ + s) * DHEAD + d8 * 8];
    #pragma unroll
    for (int k = 0; k < 8; ++k) acc[k] += bf2f(e[k]);
    lsum += lP[(q * NBH + bh) * SEQ + s];
  }
  float linv = 1.0f / lsum;
  s16x8 r;
  #pragma unroll
  for (int k = 0; k < 8; ++k) r[k] = f2bf(acc[k] * linv);
  int b = bh >> 4, h = bh & 15;
  *(s16x8*)&ob[(b * SEQ + s) * DMODEL + h * DHEAD + d8 * 8] = r;
}

extern "C" void kernel_launch(void* const* d_in, const int* in_sizes, int n_in,
                              void* d_out, int out_size, void* d_ws, size_t ws_size,
                              hipStream_t stream) {
  const float* x  = (const float*)d_in[0];
  const float* Wq = (const float*)d_in[1];
  const float* bq = (const float*)d_in[2];
  const float* Wk = (const float*)d_in[3];
  const float* bk = (const float*)d_in[4];
  const float* Wv = (const float*)d_in[5];
  const float* bv = (const float*)d_in[6];
  const float* Wo = (const float*)d_in[7];
  float* out = (float*)d_out;

  char* ws = (char*)d_ws;                         // ws is 256 MB (measured R7)
  short* xb  = (short*)(ws);                      // 8 MB  x bf16
  short* wtq = (short*)(ws + (8u  << 20));        // 6 MB  [Wq^T;Wk^T;Wv^T] bf16
  short* wto = (short*)(ws + (14u << 20));        // 2 MB  Wo^T bf16
  short* qb  = (short*)(ws + (16u << 20));        // 8 MB  Q (x 0.125*log2e folded)
  short* kb  = (short*)(ws + (24u << 20));        // 8 MB  K
  short* vt  = (short*)(ws + (32u << 20));        // 8 MB  V^T [bh][d][s]
  short* ob  = (short*)(ws + (40u << 20));        // 8 MB  attn out bf16
  short* oP  = (short*)(ws + (48u << 20));        // 32 MB o-partials [4][32][2048][64]
  float* lP  = (float*)(ws + (80u << 20));        // 1 MB  l-partials [4][32][2048]

  prep_fused<<<dim3(32, 32, 8), dim3(32, 8), 0, stream>>>(x, xb, Wq, Wk, Wv, Wo, wtq, wto);

  gemm_bf16<128, 128, 0><<<dim3(3 * DMODEL / 128, MROWS / 128), 256, 0, stream>>>(
      xb, wtq, bq, bk, bv, qb, kb, vt, nullptr);

  attn_k<<<8 * NBH * 4, 256, 0, stream>>>(qb, kb, vt, oP, lP);
  attn_merge<<<NBH * SEQ * 8 / 256, 256, 0, stream>>>(oP, lP, ob);

  gemm_bf16<64, 128, 1><<<dim3(DMODEL / 128, MROWS / 64), 256, 0, stream>>>(
      ob, wto, nullptr, nullptr, nullptr, nullptr, nullptr, nullptr, out);
}

// Round 9
// 206.489 us; speedup vs baseline: 1.0339x; 1.0339x over previous
//
#include <hip/hip_runtime.h>
#include <hip/hip_bf16.h>

// ---------- problem constants ----------
#define BATCH   2
#define SEQ     2048
#define DMODEL  1024
#define NHEADS  16
#define DHEAD   64
#define MROWS   (BATCH*SEQ)     // 4096
#define NBH     (BATCH*NHEADS)  // 32

typedef float  f32x4  __attribute__((ext_vector_type(4)));
typedef short  s16x4  __attribute__((ext_vector_type(4)));
typedef short  s16x8  __attribute__((ext_vector_type(8)));
typedef __bf16 bf16x8 __attribute__((ext_vector_type(8)));

__device__ __forceinline__ short f2bf(float f) {
  union { float f; unsigned u; } v; v.f = f;
  return (short)((v.u + 0x7fffu + ((v.u >> 16) & 1u)) >> 16);  // RNE
}
__device__ __forceinline__ float bf2f(short s) {
  union { unsigned u; float f; } v; v.u = ((unsigned)(unsigned short)s) << 16;
  return v.f;
}

// ---------- fused prep: z<4 -> W transpose+bf16; z>=4 -> x fp32->bf16 -------
__global__ void prep_fused(const float* __restrict__ x, short* __restrict__ xb,
                           const float* __restrict__ Wq, const float* __restrict__ Wk,
                           const float* __restrict__ Wv, const float* __restrict__ Wo,
                           short* __restrict__ WtQKV, short* __restrict__ WtO) {
  __shared__ float t[32][33];
  int z = blockIdx.z;
  int tx = threadIdx.x, ty = threadIdx.y;           // block (32,8)
  if (z >= 4) {                                     // convert x chunk
    int blk = (z - 4) * 1024 + blockIdx.y * 32 + blockIdx.x;
    int i = (blk * 256 + ty * 32 + tx) * 4;
    float4 v = *(const float4*)(x + i);
    s16x4 o = { f2bf(v.x), f2bf(v.y), f2bf(v.z), f2bf(v.w) };
    *(s16x4*)(xb + i) = o;
    return;
  }
  const float* W; short* Wt;
  if      (z == 0) { W = Wq; Wt = WtQKV; }
  else if (z == 1) { W = Wk; Wt = WtQKV + (1u << 20); }
  else if (z == 2) { W = Wv; Wt = WtQKV + (2u << 20); }
  else             { W = Wo; Wt = WtO; }
  int n0 = blockIdx.x * 32, k0 = blockIdx.y * 32;
  #pragma unroll
  for (int i = 0; i < 32; i += 8) t[ty + i][tx] = W[(k0 + ty + i) * DMODEL + n0 + tx];
  __syncthreads();
  #pragma unroll
  for (int i = 0; i < 32; i += 8) Wt[(n0 + ty + i) * DMODEL + k0 + tx] = f2bf(t[tx][ty + i]);
}

// ---------- bf16 GEMM: C = A[M][K] * Wt[N][K]^T, BK=64 (half the barriers) ---
template<int MT, int NT, int EPI>
__global__ __launch_bounds__(256) void gemm_bf16(
    const short* __restrict__ A, const short* __restrict__ Bt,
    const float* __restrict__ bq, const float* __restrict__ bk, const float* __restrict__ bv,
    short* __restrict__ qb, short* __restrict__ kb, short* __restrict__ vt,
    float* __restrict__ out)
{
  constexpr int K = DMODEL, BK = 64;
  constexpr int WM = MT / 2, WN = NT / 2;
  constexpr int TM = WM / 16, TN = WN / 16;
  constexpr int CA = MT * BK / 512;                  // 1KB chunks (8 rows x 64)
  constexpr int CB = NT * BK / 512;
  constexpr int TP = 136;                            // epilogue tile pitch (shorts)
  constexpr int STG = (MT + NT) * BK;
  constexpr int SME = (EPI == 0) ? (STG > 128 * TP ? STG : 128 * TP) : STG;
  __shared__ short smem[SME];
  short* la = smem;
  short* lb = smem + MT * BK;
  const int tid = threadIdx.x;
  const int wave = tid >> 6, lane = tid & 63;
  const int quad = lane >> 4, l16 = lane & 15;
  const int wr = wave >> 1, wc = wave & 1;
  const int m0 = blockIdx.y * MT, n0 = blockIdx.x * NT;
  const int arow = lane >> 3, acol = (lane & 7) * 8; // slot in a 1KB chunk (8 rows)

  f32x4 acc[TM][TN] = {};

  for (int k0 = 0; k0 < K; k0 += BK) {
    for (int c = wave; c < CA; c += 4) {
      const short* gp = A + (m0 + c * 8 + arow) * K + k0 + acol;
      __builtin_amdgcn_global_load_lds((__attribute__((address_space(1))) void*)gp,
                                       (__attribute__((address_space(3))) void*)(la + c * 512),
                                       16, 0, 0);
    }
    for (int c = wave; c < CB; c += 4) {
      const short* gp = Bt + (n0 + c * 8 + arow) * K + k0 + acol;
      __builtin_amdgcn_global_load_lds((__attribute__((address_space(1))) void*)gp,
                                       (__attribute__((address_space(3))) void*)(lb + c * 512),
                                       16, 0, 0);
    }
    __syncthreads();
    bf16x8 af[TM][2], bfr[TN][2];
    #pragma unroll
    for (int i = 0; i < TM; ++i)
      #pragma unroll
      for (int h = 0; h < 2; ++h)
        af[i][h] = *(const bf16x8*)&la[(wr * WM + i * 16 + l16) * BK + h * 32 + quad * 8];
    #pragma unroll
    for (int j = 0; j < TN; ++j)
      #pragma unroll
      for (int h = 0; h < 2; ++h)
        bfr[j][h] = *(const bf16x8*)&lb[(wc * WN + j * 16 + l16) * BK + h * 32 + quad * 8];
    #pragma unroll
    for (int i = 0; i < TM; ++i)
      #pragma unroll
      for (int j = 0; j < TN; ++j) {
        acc[i][j] = __builtin_amdgcn_mfma_f32_16x16x32_bf16(af[i][0], bfr[j][0], acc[i][j], 0, 0, 0);
        acc[i][j] = __builtin_amdgcn_mfma_f32_16x16x32_bf16(af[i][1], bfr[j][1], acc[i][j], 0, 0, 0);
      }
    __syncthreads();
  }

  if constexpr (EPI == 0) {
    const bool isV = (n0 >= 2 * DMODEL);
    const float* bias; int nbase; float scl;
    // Q scale folds 1/sqrt(Dh) AND log2(e) so attention uses exp2 directly.
    if (n0 < DMODEL)          { bias = bq; nbase = 0;          scl = 0.125f * 1.44269504089f; }
    else if (n0 < 2 * DMODEL) { bias = bk; nbase = DMODEL;     scl = 1.f; }
    else                      { bias = bv; nbase = 2 * DMODEL; scl = 1.f; }
    #pragma unroll
    for (int j = 0; j < TN; ++j) {
      int coll = wc * WN + j * 16 + l16;
      float bias_v = bias[n0 - nbase + coll];
      #pragma unroll
      for (int i = 0; i < TM; ++i) {
        int rowl = wr * WM + i * 16 + quad * 4;
        #pragma unroll
        for (int r = 0; r < 4; ++r) {
          short v = f2bf((acc[i][j][r] + bias_v) * scl);
          if (isV) smem[coll * TP + rowl + r] = v;   // transposed for V
          else     smem[(rowl + r) * TP + coll] = v;
        }
      }
    }
    __syncthreads();
    const int b = m0 >> 11, s0 = m0 & (SEQ - 1);
    const int rseg = tid & 15, rrow = tid >> 4;
    if (!isV) {
      short* dst = (n0 < DMODEL) ? qb : kb;
      #pragma unroll
      for (int it = 0; it < 8; ++it) {
        int row = it * 16 + rrow;
        int colg = (n0 - nbase) + rseg * 8;
        int h = colg >> 6, d = colg & 63;
        s16x8 v = *(const s16x8*)&smem[row * TP + rseg * 8];
        *(s16x8*)(dst + ((b * NHEADS + h) * SEQ + s0 + row) * DHEAD + d) = v;
      }
    } else {
      #pragma unroll
      for (int it = 0; it < 8; ++it) {
        int drow = it * 16 + rrow;
        int colg = (n0 - nbase) + drow;
        int h = colg >> 6, d = colg & 63;
        s16x8 v = *(const s16x8*)&smem[drow * TP + rseg * 8];
        *(s16x8*)(vt + ((b * NHEADS + h) * DHEAD + d) * SEQ + s0 + rseg * 8) = v;
      }
    }
  } else {
    #pragma unroll
    for (int i = 0; i < TM; ++i)
      #pragma unroll
      for (int r = 0; r < 4; ++r) {
        int mrow = m0 + wr * WM + i * 16 + quad * 4 + r;
        #pragma unroll
        for (int j = 0; j < TN; ++j)
          out[mrow * DMODEL + n0 + wc * WN + j * 16 + l16] = acc[i][j][r];
      }
    (void)bq; (void)bk; (void)bv; (void)qb; (void)kb; (void)vt;
  }
}

// ================= flash attention v8: R7 split-2 + dual-chunk stages =========
// R8 post-mortem: quarter-split regressed (4-way T-scatter broke L2 locality;
// barrier drains became HBM-latency). Revert to split-2 (L2-served, FETCH
// ~19MB). New lever: TWO chunks staged per barrier (2 bufs x 16KB = 64KB LDS,
// same 2 blocks/CU) -> half the __syncthreads / vmcnt(0) drains, each
// amortized over 2x compute. 4 frags/wave kept (LDS-read amortization, R7).
// Softmax: unnormalized exp2 per-lane (scale*log2e folded into Q); halves
// merge by pure addition in attn_merge.

__global__ __launch_bounds__(256, 2) void attn_k(
    const short* __restrict__ qbp, const short* __restrict__ kbp,
    const short* __restrict__ vtb, short* __restrict__ oP, float* __restrict__ lP)
{
  __shared__ short kls[2][8192];                    // 2 bufs x (2 chunks x 8KB)
  __shared__ short vls[2][8192];
  const int tid = threadIdx.x, wave = tid >> 6, lane = tid & 63;
  const int quad = lane >> 4, l16 = lane & 15;
  const int half = blockIdx.x & 1;
  const int bh = (blockIdx.x >> 1) & 31;
  const int qg = blockIdx.x >> 6;                   // 0..7, long (qg=0) first
  const int qt1 = qg * 8 + wave * 2;                // 0..62 even
  // fragment rows (ascending): pairs (qt1,127-qt1),(qt1+1,126-qt1)
  const int mF[4] = { qt1 * 16, (qt1 + 1) * 16, (126 - qt1) * 16, (127 - qt1) * 16 };
  const int nch = (127 - 8 * qg) / 4 + 1;          // block-uniform chunk count
  const short* Q  = qbp + bh * SEQ * DHEAD;
  const short* Kp = kbp + bh * SEQ * DHEAD;
  const short* Vt = vtb + bh * DHEAD * SEQ;

  bf16x8 qf[4][2];
  #pragma unroll
  for (int f = 0; f < 4; ++f) {
    qf[f][0] = *(const bf16x8*)&Q[(mF[f] + l16) * DHEAD + quad * 8];
    qf[f][1] = *(const bf16x8*)&Q[(mF[f] + l16) * DHEAD + 32 + quad * 8];
  }

  float lF[4] = {};
  f32x4 oF[4][4] = {};

  const int vdl = lane >> 3, vsl = lane & 7;        // V staging lane split

  auto stage1 = [&](int buf, int slot, int t0) {    // one 64-t chunk
    #pragma unroll
    for (int j = 0; j < 2; ++j) {
      int g = j * 4 + wave;                         // K ch-group 0..7
      const short* gp = Kp + (t0 + lane) * DHEAD + g * 8;
      __builtin_amdgcn_global_load_lds((__attribute__((address_space(1))) void*)gp,
                                       (__attribute__((address_space(3))) void*)&kls[buf][slot * 4096 + g * 512],
                                       16, 0, 0);
    }
    #pragma unroll
    for (int j = 0; j < 2; ++j) {
      int gd = j * 4 + wave;                        // V d-block 0..7
      const short* gp = Vt + (gd * 8 + vdl) * SEQ + t0 + ((vsl ^ vdl) * 8);
      __builtin_amdgcn_global_load_lds((__attribute__((address_space(1))) void*)gp,
                                       (__attribute__((address_space(3))) void*)&vls[buf][slot * 4096 + gd * 512],
                                       16, 0, 0);
    }
  };
  auto stagepair = [&](int buf, int cc) {           // chunks cc, cc+2 (owned set)
    stage1(buf, 0, cc * 64);
    if (cc + 2 < nch) stage1(buf, 1, (cc + 2) * 64);
  };

  stagepair(0, half);
  int it = 0;
  for (int cc = half; cc < nch; cc += 4, ++it) {
    __syncthreads();                                // drains stagepair; waves synced
    if (cc + 4 < nch) stagepair((it + 1) & 1, cc + 4);
    const int buf = it & 1;
    #pragma unroll
    for (int u = 0; u < 2; ++u) {                   // chunk within pair
      const int c = cc + 2 * u;
      if (c < nch) {                                // block-uniform
        const int t0 = c * 64;
        const int sb = u * 4096;
        #pragma unroll
        for (int t = 0; t < 4; ++t) {
          const int tb = t0 + t * 16;
          if (tb <= mF[3]) {                        // any fragment live (wave-uniform)
            bf16x8 kf0 = *(const bf16x8*)&kls[buf][sb + ((0 + quad) * 64 + t * 16 + l16) * 8];
            bf16x8 kf1 = *(const bf16x8*)&kls[buf][sb + ((4 + quad) * 64 + t * 16 + l16) * 8];
            s16x4 vf[4];
            {
              int gsw = ((t * 2 + (quad >> 1)) ^ (l16 & 7));
              #pragma unroll
              for (int dt = 0; dt < 4; ++dt)
                vf[dt] = *(const s16x4*)&vls[buf][sb + ((dt * 16 + l16) * 8 + gsw) * 8 + (quad & 1) * 4];
            }
            #pragma unroll
            for (int f = 0; f < 4; ++f) {
              if (tb <= mF[f]) {                    // wave-uniform
                f32x4 a = {};
                a = __builtin_amdgcn_mfma_f32_16x16x32_bf16(kf0, qf[f][0], a, 0, 0, 0);
                a = __builtin_amdgcn_mfma_f32_16x16x32_bf16(kf1, qf[f][1], a, 0, 0, 0);
                if (tb == mF[f]) {                  // diagonal: mask t > m
                  #pragma unroll
                  for (int r = 0; r < 4; ++r)
                    if (quad * 4 + r > l16) a[r] = -1e30f;
                }
                f32x4 p;
                #pragma unroll
                for (int r = 0; r < 4; ++r) p[r] = __builtin_amdgcn_exp2f(a[r]);
                lF[f] += (p[0] + p[1]) + (p[2] + p[3]);
                __hip_bfloat162 c01 = __float22bfloat162_rn(float2{p[0], p[1]});
                __hip_bfloat162 c23 = __float22bfloat162_rn(float2{p[2], p[3]});
                union { unsigned u2[2]; s16x4 s; } pu;
                pu.u2[0] = *(unsigned*)&c01; pu.u2[1] = *(unsigned*)&c23;
                #pragma unroll
                for (int dt = 0; dt < 4; ++dt)
                  oF[f][dt] = __builtin_amdgcn_mfma_f32_16x16x16bf16_1k(pu.s, vf[dt], oF[f][dt], 0, 0, 0);
              }
            }
          }
        }
      }
    }
  }

  // reduce l across quads; store partials [half][bh][s][64]
  float* lD = lP + (half * NBH + bh) * SEQ;
  short* oD = oP + ((half * NBH + bh) * SEQ) * DHEAD;
  #pragma unroll
  for (int f = 0; f < 4; ++f) {
    float l = lF[f];
    l += __shfl_xor(l, 16, 64); l += __shfl_xor(l, 32, 64);
    if (quad == 0) lD[mF[f] + l16] = l;
    #pragma unroll
    for (int r = 0; r < 4; ++r) {
      int s = mF[f] + quad * 4 + r;
      #pragma unroll
      for (int dt = 0; dt < 4; ++dt)
        oD[s * DHEAD + dt * 16 + l16] = f2bf(oF[f][dt][r]);
    }
  }
}

// ---------- merge halves: ob = (oE + oO) / (lE + lO), bf16 [b][s][h*64+d] ----
__global__ void attn_merge(const short* __restrict__ oP, const float* __restrict__ lP,
                           short* __restrict__ ob) {
  int idx = blockIdx.x * 256 + threadIdx.x;         // one thread = 8 outputs
  int d8 = idx & 7, s = (idx >> 3) & (SEQ - 1), bh = idx >> 14;
  s16x8 e = *(const s16x8*)&oP[((0   + bh) * SEQ + s) * DHEAD + d8 * 8];
  s16x8 o = *(const s16x8*)&oP[((NBH + bh) * SEQ + s) * DHEAD + d8 * 8];
  float linv = 1.0f / (lP[bh * SEQ + s] + lP[(NBH + bh) * SEQ + s]);
  s16x8 r;
  #pragma unroll
  for (int k = 0; k < 8; ++k) r[k] = f2bf((bf2f(e[k]) + bf2f(o[k])) * linv);
  int b = bh >> 4, h = bh & 15;
  *(s16x8*)&ob[(b * SEQ + s) * DMODEL + h * DHEAD + d8 * 8] = r;
}

extern "C" void kernel_launch(void* const* d_in, const int* in_sizes, int n_in,
                              void* d_out, int out_size, void* d_ws, size_t ws_size,
                              hipStream_t stream) {
  const float* x  = (const float*)d_in[0];
  const float* Wq = (const float*)d_in[1];
  const float* bq = (const float*)d_in[2];
  const float* Wk = (const float*)d_in[3];
  const float* bk = (const float*)d_in[4];
  const float* Wv = (const float*)d_in[5];
  const float* bv = (const float*)d_in[6];
  const float* Wo = (const float*)d_in[7];
  float* out = (float*)d_out;

  char* ws = (char*)d_ws;                         // ws is 256 MB (measured R7)
  short* xb  = (short*)(ws);                      // 8 MB  x bf16
  short* wtq = (short*)(ws + (8u  << 20));        // 6 MB  [Wq^T;Wk^T;Wv^T] bf16
  short* wto = (short*)(ws + (14u << 20));        // 2 MB  Wo^T bf16
  short* qb  = (short*)(ws + (16u << 20));        // 8 MB  Q (x 0.125*log2e folded)
  short* kb  = (short*)(ws + (24u << 20));        // 8 MB  K
  short* vt  = (short*)(ws + (32u << 20));        // 8 MB  V^T [bh][d][s]
  short* ob  = (short*)(ws + (40u << 20));        // 8 MB  attn out bf16
  short* oP  = (short*)(ws + (48u << 20));        // 16 MB o-partials [2][32][2048][64]
  float* lP  = (float*)(ws + (80u << 20));        // 0.5MB l-partials [2][32][2048]

  prep_fused<<<dim3(32, 32, 8), dim3(32, 8), 0, stream>>>(x, xb, Wq, Wk, Wv, Wo, wtq, wto);

  gemm_bf16<128, 128, 0><<<dim3(3 * DMODEL / 128, MROWS / 128), 256, 0, stream>>>(
      xb, wtq, bq, bk, bv, qb, kb, vt, nullptr);

  attn_k<<<8 * NBH * 2, 256, 0, stream>>>(qb, kb, vt, oP, lP);
  attn_merge<<<NBH * SEQ * 8 / 256, 256, 0, stream>>>(oP, lP, ob);

  gemm_bf16<64, 128, 1><<<dim3(DMODEL / 128, MROWS / 64), 256, 0, stream>>>(
      ob, wto, nullptr, nullptr, nullptr, nullptr, nullptr, nullptr, out);
}

// Round 10
// 201.201 us; speedup vs baseline: 1.0610x; 1.0263x over previous
//
#include <hip/hip_runtime.h>
#include <hip/hip_bf16.h>

// ---------- problem constants ----------
#define BATCH   2
#define SEQ     2048
#define DMODEL  1024
#define NHEADS  16
#define DHEAD   64
#define MROWS   (BATCH*SEQ)     // 4096
#define NBH     (BATCH*NHEADS)  // 32

typedef float  f32x4  __attribute__((ext_vector_type(4)));
typedef short  s16x4  __attribute__((ext_vector_type(4)));
typedef short  s16x8  __attribute__((ext_vector_type(8)));
typedef __bf16 bf16x8 __attribute__((ext_vector_type(8)));

__device__ __forceinline__ short f2bf(float f) {
  union { float f; unsigned u; } v; v.f = f;
  return (short)((v.u + 0x7fffu + ((v.u >> 16) & 1u)) >> 16);  // RNE
}
__device__ __forceinline__ float bf2f(short s) {
  union { unsigned u; float f; } v; v.u = ((unsigned)(unsigned short)s) << 16;
  return v.f;
}

// ---------- fused prep: z<4 -> W transpose+bf16; z>=4 -> x fp32->bf16 -------
__global__ void prep_fused(const float* __restrict__ x, short* __restrict__ xb,
                           const float* __restrict__ Wq, const float* __restrict__ Wk,
                           const float* __restrict__ Wv, const float* __restrict__ Wo,
                           short* __restrict__ WtQKV, short* __restrict__ WtO) {
  __shared__ float t[32][33];
  int z = blockIdx.z;
  int tx = threadIdx.x, ty = threadIdx.y;           // block (32,8)
  if (z >= 4) {                                     // convert x chunk
    int blk = (z - 4) * 1024 + blockIdx.y * 32 + blockIdx.x;
    int i = (blk * 256 + ty * 32 + tx) * 4;
    float4 v = *(const float4*)(x + i);
    s16x4 o = { f2bf(v.x), f2bf(v.y), f2bf(v.z), f2bf(v.w) };
    *(s16x4*)(xb + i) = o;
    return;
  }
  const float* W; short* Wt;
  if      (z == 0) { W = Wq; Wt = WtQKV; }
  else if (z == 1) { W = Wk; Wt = WtQKV + (1u << 20); }
  else if (z == 2) { W = Wv; Wt = WtQKV + (2u << 20); }
  else             { W = Wo; Wt = WtO; }
  int n0 = blockIdx.x * 32, k0 = blockIdx.y * 32;
  #pragma unroll
  for (int i = 0; i < 32; i += 8) t[ty + i][tx] = W[(k0 + ty + i) * DMODEL + n0 + tx];
  __syncthreads();
  #pragma unroll
  for (int i = 0; i < 32; i += 8) Wt[(n0 + ty + i) * DMODEL + k0 + tx] = f2bf(t[tx][ty + i]);
}

// ---------- bf16 GEMM: C = A[M][K] * Wt[N][K]^T -------------------------------
// R9 post-mortem: BK=64 (128B LDS row stride = 32 banks) made every b128 read
// a 16-way bank conflict (9.67M SQ_LDS_BANK_CONFLICT). v3: two independent
// BK=32 slabs per barrier - keeps the conflict-free 64B-stride layout AND
// halves the barrier count. Same global_load_lds count as BK=32.
template<int MT, int NT, int EPI>
__global__ __launch_bounds__(256) void gemm_bf16(
    const short* __restrict__ A, const short* __restrict__ Bt,
    const float* __restrict__ bq, const float* __restrict__ bk, const float* __restrict__ bv,
    short* __restrict__ qb, short* __restrict__ kb, short* __restrict__ vt,
    float* __restrict__ out)
{
  constexpr int K = DMODEL, BK = 32;
  constexpr int WM = MT / 2, WN = NT / 2;
  constexpr int TM = WM / 16, TN = WN / 16;
  constexpr int CA = MT * BK / 512;                  // 1KB chunks per slab
  constexpr int CB = NT * BK / 512;
  constexpr int TP = 136;                            // epilogue tile pitch (shorts)
  constexpr int STG = (MT + NT) * BK * 2;            // two slabs
  constexpr int SME = (EPI == 0) ? (STG > 128 * TP ? STG : 128 * TP) : STG;
  __shared__ short smem[SME];
  short* la = smem;                                  // [2][MT*BK]
  short* lb = smem + 2 * MT * BK;                    // [2][NT*BK]
  const int tid = threadIdx.x;
  const int wave = tid >> 6, lane = tid & 63;
  const int quad = lane >> 4, l16 = lane & 15;
  const int wr = wave >> 1, wc = wave & 1;
  const int m0 = blockIdx.y * MT, n0 = blockIdx.x * NT;
  const int arow = lane >> 2, acol = (lane & 3) * 8;

  f32x4 acc[TM][TN] = {};

  for (int k0 = 0; k0 < K; k0 += 2 * BK) {
    #pragma unroll
    for (int s = 0; s < 2; ++s) {
      for (int c = wave; c < CA; c += 4) {
        const short* gp = A + (m0 + c * 16 + arow) * K + k0 + s * BK + acol;
        __builtin_amdgcn_global_load_lds((__attribute__((address_space(1))) void*)gp,
                                         (__attribute__((address_space(3))) void*)(la + s * MT * BK + c * 512),
                                         16, 0, 0);
      }
      for (int c = wave; c < CB; c += 4) {
        const short* gp = Bt + (n0 + c * 16 + arow) * K + k0 + s * BK + acol;
        __builtin_amdgcn_global_load_lds((__attribute__((address_space(1))) void*)gp,
                                         (__attribute__((address_space(3))) void*)(lb + s * NT * BK + c * 512),
                                         16, 0, 0);
      }
    }
    __syncthreads();
    #pragma unroll
    for (int s = 0; s < 2; ++s) {                    // per-slab: transients die early
      bf16x8 af[TM], bfr[TN];
      #pragma unroll
      for (int i = 0; i < TM; ++i)
        af[i] = *(const bf16x8*)&la[s * MT * BK + (wr * WM + i * 16 + l16) * BK + quad * 8];
      #pragma unroll
      for (int j = 0; j < TN; ++j)
        bfr[j] = *(const bf16x8*)&lb[s * NT * BK + (wc * WN + j * 16 + l16) * BK + quad * 8];
      #pragma unroll
      for (int i = 0; i < TM; ++i)
        #pragma unroll
        for (int j = 0; j < TN; ++j)
          acc[i][j] = __builtin_amdgcn_mfma_f32_16x16x32_bf16(af[i], bfr[j], acc[i][j], 0, 0, 0);
    }
    __syncthreads();
  }

  if constexpr (EPI == 0) {
    const bool isV = (n0 >= 2 * DMODEL);
    const float* bias; int nbase; float scl;
    // Q scale folds 1/sqrt(Dh) AND log2(e) so attention uses exp2 directly.
    if (n0 < DMODEL)          { bias = bq; nbase = 0;          scl = 0.125f * 1.44269504089f; }
    else if (n0 < 2 * DMODEL) { bias = bk; nbase = DMODEL;     scl = 1.f; }
    else                      { bias = bv; nbase = 2 * DMODEL; scl = 1.f; }
    #pragma unroll
    for (int j = 0; j < TN; ++j) {
      int coll = wc * WN + j * 16 + l16;
      float bias_v = bias[n0 - nbase + coll];
      #pragma unroll
      for (int i = 0; i < TM; ++i) {
        int rowl = wr * WM + i * 16 + quad * 4;
        #pragma unroll
        for (int r = 0; r < 4; ++r) {
          short v = f2bf((acc[i][j][r] + bias_v) * scl);
          if (isV) smem[coll * TP + rowl + r] = v;   // transposed for V
          else     smem[(rowl + r) * TP + coll] = v;
        }
      }
    }
    __syncthreads();
    const int b = m0 >> 11, s0 = m0 & (SEQ - 1);
    const int rseg = tid & 15, rrow = tid >> 4;
    if (!isV) {
      short* dst = (n0 < DMODEL) ? qb : kb;
      #pragma unroll
      for (int it = 0; it < 8; ++it) {
        int row = it * 16 + rrow;
        int colg = (n0 - nbase) + rseg * 8;
        int h = colg >> 6, d = colg & 63;
        s16x8 v = *(const s16x8*)&smem[row * TP + rseg * 8];
        *(s16x8*)(dst + ((b * NHEADS + h) * SEQ + s0 + row) * DHEAD + d) = v;
      }
    } else {
      #pragma unroll
      for (int it = 0; it < 8; ++it) {
        int drow = it * 16 + rrow;
        int colg = (n0 - nbase) + drow;
        int h = colg >> 6, d = colg & 63;
        s16x8 v = *(const s16x8*)&smem[drow * TP + rseg * 8];
        *(s16x8*)(vt + ((b * NHEADS + h) * DHEAD + d) * SEQ + s0 + rseg * 8) = v;
      }
    }
  } else {
    #pragma unroll
    for (int i = 0; i < TM; ++i)
      #pragma unroll
      for (int r = 0; r < 4; ++r) {
        int mrow = m0 + wr * WM + i * 16 + quad * 4 + r;
        #pragma unroll
        for (int j = 0; j < TN; ++j)
          out[mrow * DMODEL + n0 + wc * WN + j * 16 + l16] = acc[i][j][r];
      }
    (void)bq; (void)bk; (void)bv; (void)qb; (void)kb; (void)vt;
  }
}

// ================= flash attention v8 (kept from R9): split-2 + dual-chunk ====
// Split-2 T-halves (L2-served staging), 4 frags/wave, TWO chunks staged per
// barrier (half the vmcnt(0) drains). Softmax: unnormalized exp2 per-lane
// (scale*log2e folded into Q); halves merge by pure addition in attn_merge.

__global__ __launch_bounds__(256, 2) void attn_k(
    const short* __restrict__ qbp, const short* __restrict__ kbp,
    const short* __restrict__ vtb, short* __restrict__ oP, float* __restrict__ lP)
{
  __shared__ short kls[2][8192];                    // 2 bufs x (2 chunks x 8KB)
  __shared__ short vls[2][8192];
  const int tid = threadIdx.x, wave = tid >> 6, lane = tid & 63;
  const int quad = lane >> 4, l16 = lane & 15;
  const int half = blockIdx.x & 1;
  const int bh = (blockIdx.x >> 1) & 31;
  const int qg = blockIdx.x >> 6;                   // 0..7, long (qg=0) first
  const int qt1 = qg * 8 + wave * 2;                // 0..62 even
  const int mF[4] = { qt1 * 16, (qt1 + 1) * 16, (126 - qt1) * 16, (127 - qt1) * 16 };
  const int nch = (127 - 8 * qg) / 4 + 1;          // block-uniform chunk count
  const short* Q  = qbp + bh * SEQ * DHEAD;
  const short* Kp = kbp + bh * SEQ * DHEAD;
  const short* Vt = vtb + bh * DHEAD * SEQ;

  bf16x8 qf[4][2];
  #pragma unroll
  for (int f = 0; f < 4; ++f) {
    qf[f][0] = *(const bf16x8*)&Q[(mF[f] + l16) * DHEAD + quad * 8];
    qf[f][1] = *(const bf16x8*)&Q[(mF[f] + l16) * DHEAD + 32 + quad * 8];
  }

  float lF[4] = {};
  f32x4 oF[4][4] = {};

  const int vdl = lane >> 3, vsl = lane & 7;        // V staging lane split

  auto stage1 = [&](int buf, int slot, int t0) {    // one 64-t chunk
    #pragma unroll
    for (int j = 0; j < 2; ++j) {
      int g = j * 4 + wave;                         // K ch-group 0..7
      const short* gp = Kp + (t0 + lane) * DHEAD + g * 8;
      __builtin_amdgcn_global_load_lds((__attribute__((address_space(1))) void*)gp,
                                       (__attribute__((address_space(3))) void*)&kls[buf][slot * 4096 + g * 512],
                                       16, 0, 0);
    }
    #pragma unroll
    for (int j = 0; j < 2; ++j) {
      int gd = j * 4 + wave;                        // V d-block 0..7
      const short* gp = Vt + (gd * 8 + vdl) * SEQ + t0 + ((vsl ^ vdl) * 8);
      __builtin_amdgcn_global_load_lds((__attribute__((address_space(1))) void*)gp,
                                       (__attribute__((address_space(3))) void*)&vls[buf][slot * 4096 + gd * 512],
                                       16, 0, 0);
    }
  };
  auto stagepair = [&](int buf, int cc) {           // chunks cc, cc+2 (owned set)
    stage1(buf, 0, cc * 64);
    if (cc + 2 < nch) stage1(buf, 1, (cc + 2) * 64);
  };

  stagepair(0, half);
  int it = 0;
  for (int cc = half; cc < nch; cc += 4, ++it) {
    __syncthreads();                                // drains stagepair; waves synced
    if (cc + 4 < nch) stagepair((it + 1) & 1, cc + 4);
    const int buf = it & 1;
    #pragma unroll
    for (int u = 0; u < 2; ++u) {                   // chunk within pair
      const int c = cc + 2 * u;
      if (c < nch) {                                // block-uniform
        const int t0 = c * 64;
        const int sb = u * 4096;
        #pragma unroll
        for (int t = 0; t < 4; ++t) {
          const int tb = t0 + t * 16;
          if (tb <= mF[3]) {                        // any fragment live (wave-uniform)
            bf16x8 kf0 = *(const bf16x8*)&kls[buf][sb + ((0 + quad) * 64 + t * 16 + l16) * 8];
            bf16x8 kf1 = *(const bf16x8*)&kls[buf][sb + ((4 + quad) * 64 + t * 16 + l16) * 8];
            s16x4 vf[4];
            {
              int gsw = ((t * 2 + (quad >> 1)) ^ (l16 & 7));
              #pragma unroll
              for (int dt = 0; dt < 4; ++dt)
                vf[dt] = *(const s16x4*)&vls[buf][sb + ((dt * 16 + l16) * 8 + gsw) * 8 + (quad & 1) * 4];
            }
            #pragma unroll
            for (int f = 0; f < 4; ++f) {
              if (tb <= mF[f]) {                    // wave-uniform
                f32x4 a = {};
                a = __builtin_amdgcn_mfma_f32_16x16x32_bf16(kf0, qf[f][0], a, 0, 0, 0);
                a = __builtin_amdgcn_mfma_f32_16x16x32_bf16(kf1, qf[f][1], a, 0, 0, 0);
                if (tb == mF[f]) {                  // diagonal: mask t > m
                  #pragma unroll
                  for (int r = 0; r < 4; ++r)
                    if (quad * 4 + r > l16) a[r] = -1e30f;
                }
                f32x4 p;
                #pragma unroll
                for (int r = 0; r < 4; ++r) p[r] = __builtin_amdgcn_exp2f(a[r]);
                lF[f] += (p[0] + p[1]) + (p[2] + p[3]);
                __hip_bfloat162 c01 = __float22bfloat162_rn(float2{p[0], p[1]});
                __hip_bfloat162 c23 = __float22bfloat162_rn(float2{p[2], p[3]});
                union { unsigned u2[2]; s16x4 s; } pu;
                pu.u2[0] = *(unsigned*)&c01; pu.u2[1] = *(unsigned*)&c23;
                #pragma unroll
                for (int dt = 0; dt < 4; ++dt)
                  oF[f][dt] = __builtin_amdgcn_mfma_f32_16x16x16bf16_1k(pu.s, vf[dt], oF[f][dt], 0, 0, 0);
              }
            }
          }
        }
      }
    }
  }

  // reduce l across quads; store partials [half][bh][s][64]
  float* lD = lP + (half * NBH + bh) * SEQ;
  short* oD = oP + ((half * NBH + bh) * SEQ) * DHEAD;
  #pragma unroll
  for (int f = 0; f < 4; ++f) {
    float l = lF[f];
    l += __shfl_xor(l, 16, 64); l += __shfl_xor(l, 32, 64);
    if (quad == 0) lD[mF[f] + l16] = l;
    #pragma unroll
    for (int r = 0; r < 4; ++r) {
      int s = mF[f] + quad * 4 + r;
      #pragma unroll
      for (int dt = 0; dt < 4; ++dt)
        oD[s * DHEAD + dt * 16 + l16] = f2bf(oF[f][dt][r]);
    }
  }
}

// ---------- merge halves: ob = (oE + oO) / (lE + lO), bf16 [b][s][h*64+d] ----
__global__ void attn_merge(const short* __restrict__ oP, const float* __restrict__ lP,
                           short* __restrict__ ob) {
  int idx = blockIdx.x * 256 + threadIdx.x;         // one thread = 8 outputs
  int d8 = idx & 7, s = (idx >> 3) & (SEQ - 1), bh = idx >> 14;
  s16x8 e = *(const s16x8*)&oP[((0   + bh) * SEQ + s) * DHEAD + d8 * 8];
  s16x8 o = *(const s16x8*)&oP[((NBH + bh) * SEQ + s) * DHEAD + d8 * 8];
  float linv = 1.0f / (lP[bh * SEQ + s] + lP[(NBH + bh) * SEQ + s]);
  s16x8 r;
  #pragma unroll
  for (int k = 0; k < 8; ++k) r[k] = f2bf((bf2f(e[k]) + bf2f(o[k])) * linv);
  int b = bh >> 4, h = bh & 15;
  *(s16x8*)&ob[(b * SEQ + s) * DMODEL + h * DHEAD + d8 * 8] = r;
}

extern "C" void kernel_launch(void* const* d_in, const int* in_sizes, int n_in,
                              void* d_out, int out_size, void* d_ws, size_t ws_size,
                              hipStream_t stream) {
  const float* x  = (const float*)d_in[0];
  const float* Wq = (const float*)d_in[1];
  const float* bq = (const float*)d_in[2];
  const float* Wk = (const float*)d_in[3];
  const float* bk = (const float*)d_in[4];
  const float* Wv = (const float*)d_in[5];
  const float* bv = (const float*)d_in[6];
  const float* Wo = (const float*)d_in[7];
  float* out = (float*)d_out;

  char* ws = (char*)d_ws;                         // ws is 256 MB (measured R7)
  short* xb  = (short*)(ws);                      // 8 MB  x bf16
  short* wtq = (short*)(ws + (8u  << 20));        // 6 MB  [Wq^T;Wk^T;Wv^T] bf16
  short* wto = (short*)(ws + (14u << 20));        // 2 MB  Wo^T bf16
  short* qb  = (short*)(ws + (16u << 20));        // 8 MB  Q (x 0.125*log2e folded)
  short* kb  = (short*)(ws + (24u << 20));        // 8 MB  K
  short* vt  = (short*)(ws + (32u << 20));        // 8 MB  V^T [bh][d][s]
  short* ob  = (short*)(ws + (40u << 20));        // 8 MB  attn out bf16
  short* oP  = (short*)(ws + (48u << 20));        // 16 MB o-partials [2][32][2048][64]
  float* lP  = (float*)(ws + (80u << 20));        // 0.5MB l-partials [2][32][2048]

  prep_fused<<<dim3(32, 32, 8), dim3(32, 8), 0, stream>>>(x, xb, Wq, Wk, Wv, Wo, wtq, wto);

  gemm_bf16<128, 128, 0><<<dim3(3 * DMODEL / 128, MROWS / 128), 256, 0, stream>>>(
      xb, wtq, bq, bk, bv, qb, kb, vt, nullptr);

  attn_k<<<8 * NBH * 2, 256, 0, stream>>>(qb, kb, vt, oP, lP);
  attn_merge<<<NBH * SEQ * 8 / 256, 256, 0, stream>>>(oP, lP, ob);

  gemm_bf16<64, 128, 1><<<dim3(DMODEL / 128, MROWS / 64), 256, 0, stream>>>(
      ob, wto, nullptr, nullptr, nullptr, nullptr, nullptr, nullptr, out);
}

// Round 11
// 189.036 us; speedup vs baseline: 1.1293x; 1.0644x over previous
//
#include <hip/hip_runtime.h>
#include <hip/hip_bf16.h>

// ---------- problem constants ----------
#define BATCH   2
#define SEQ     2048
#define DMODEL  1024
#define NHEADS  16
#define DHEAD   64
#define MROWS   (BATCH*SEQ)     // 4096
#define NBH     (BATCH*NHEADS)  // 32

typedef float  f32x4  __attribute__((ext_vector_type(4)));
typedef short  s16x4  __attribute__((ext_vector_type(4)));
typedef short  s16x8  __attribute__((ext_vector_type(8)));
typedef __bf16 bf16x8 __attribute__((ext_vector_type(8)));

__device__ __forceinline__ short f2bf(float f) {
  union { float f; unsigned u; } v; v.f = f;
  return (short)((v.u + 0x7fffu + ((v.u >> 16) & 1u)) >> 16);  // RNE
}
__device__ __forceinline__ float bf2f(short s) {
  union { unsigned u; float f; } v; v.u = ((unsigned)(unsigned short)s) << 16;
  return v.f;
}

// ---------- fused prep: z<4 -> W transpose+bf16; z>=4 -> x fp32->bf16 -------
__global__ void prep_fused(const float* __restrict__ x, short* __restrict__ xb,
                           const float* __restrict__ Wq, const float* __restrict__ Wk,
                           const float* __restrict__ Wv, const float* __restrict__ Wo,
                           short* __restrict__ WtQKV, short* __restrict__ WtO) {
  __shared__ float t[32][33];
  int z = blockIdx.z;
  int tx = threadIdx.x, ty = threadIdx.y;           // block (32,8)
  if (z >= 4) {                                     // convert x chunk
    int blk = (z - 4) * 1024 + blockIdx.y * 32 + blockIdx.x;
    int i = (blk * 256 + ty * 32 + tx) * 4;
    float4 v = *(const float4*)(x + i);
    s16x4 o = { f2bf(v.x), f2bf(v.y), f2bf(v.z), f2bf(v.w) };
    *(s16x4*)(xb + i) = o;
    return;
  }
  const float* W; short* Wt;
  if      (z == 0) { W = Wq; Wt = WtQKV; }
  else if (z == 1) { W = Wk; Wt = WtQKV + (1u << 20); }
  else if (z == 2) { W = Wv; Wt = WtQKV + (2u << 20); }
  else             { W = Wo; Wt = WtO; }
  int n0 = blockIdx.x * 32, k0 = blockIdx.y * 32;
  #pragma unroll
  for (int i = 0; i < 32; i += 8) t[ty + i][tx] = W[(k0 + ty + i) * DMODEL + n0 + tx];
  __syncthreads();
  #pragma unroll
  for (int i = 0; i < 32; i += 8) Wt[(n0 + ty + i) * DMODEL + k0 + tx] = f2bf(t[tx][ty + i]);
}

// ---------- bf16 GEMM, m97 single-slab BK=32 (R4-R8 proven; R9/R10 barrier-
// halving variants both regressed ~16us -> reverted verbatim) -----------------
template<int MT, int NT, int EPI>
__global__ __launch_bounds__(256) void gemm_bf16(
    const short* __restrict__ A, const short* __restrict__ Bt,
    const float* __restrict__ bq, const float* __restrict__ bk, const float* __restrict__ bv,
    short* __restrict__ qb, short* __restrict__ kb, short* __restrict__ vt,
    float* __restrict__ out)
{
  constexpr int K = DMODEL, BK = 32;
  constexpr int WM = MT / 2, WN = NT / 2;
  constexpr int TM = WM / 16, TN = WN / 16;
  constexpr int CA = MT * BK / 512;
  constexpr int CB = NT * BK / 512;
  constexpr int TP = 136;                            // epilogue tile pitch (shorts)
  constexpr int SME = (EPI == 0) ? 128 * TP : (MT * BK + NT * BK);
  __shared__ short smem[SME];
  short* la = smem;
  short* lb = smem + MT * BK;
  const int tid = threadIdx.x;
  const int wave = tid >> 6, lane = tid & 63;
  const int quad = lane >> 4, l16 = lane & 15;
  const int wr = wave >> 1, wc = wave & 1;
  const int m0 = blockIdx.y * MT, n0 = blockIdx.x * NT;
  const int arow = lane >> 2, acol = (lane & 3) * 8;

  f32x4 acc[TM][TN] = {};

  for (int k0 = 0; k0 < K; k0 += BK) {
    for (int c = wave; c < CA; c += 4) {
      const short* gp = A + (m0 + c * 16 + arow) * K + k0 + acol;
      __builtin_amdgcn_global_load_lds((__attribute__((address_space(1))) void*)gp,
                                       (__attribute__((address_space(3))) void*)(la + c * 512),
                                       16, 0, 0);
    }
    for (int c = wave; c < CB; c += 4) {
      const short* gp = Bt + (n0 + c * 16 + arow) * K + k0 + acol;
      __builtin_amdgcn_global_load_lds((__attribute__((address_space(1))) void*)gp,
                                       (__attribute__((address_space(3))) void*)(lb + c * 512),
                                       16, 0, 0);
    }
    __syncthreads();
    bf16x8 af[TM], bfr[TN];
    #pragma unroll
    for (int i = 0; i < TM; ++i)
      af[i] = *(const bf16x8*)&la[(wr * WM + i * 16 + l16) * BK + quad * 8];
    #pragma unroll
    for (int j = 0; j < TN; ++j)
      bfr[j] = *(const bf16x8*)&lb[(wc * WN + j * 16 + l16) * BK + quad * 8];
    #pragma unroll
    for (int i = 0; i < TM; ++i)
      #pragma unroll
      for (int j = 0; j < TN; ++j)
        acc[i][j] = __builtin_amdgcn_mfma_f32_16x16x32_bf16(af[i], bfr[j], acc[i][j], 0, 0, 0);
    __syncthreads();
  }

  if constexpr (EPI == 0) {
    const bool isV = (n0 >= 2 * DMODEL);
    const float* bias; int nbase; float scl;
    // Q scale folds 1/sqrt(Dh) AND log2(e) so attention uses exp2 directly.
    if (n0 < DMODEL)          { bias = bq; nbase = 0;          scl = 0.125f * 1.44269504089f; }
    else if (n0 < 2 * DMODEL) { bias = bk; nbase = DMODEL;     scl = 1.f; }
    else                      { bias = bv; nbase = 2 * DMODEL; scl = 1.f; }
    #pragma unroll
    for (int j = 0; j < TN; ++j) {
      int coll = wc * WN + j * 16 + l16;
      float bias_v = bias[n0 - nbase + coll];
      #pragma unroll
      for (int i = 0; i < TM; ++i) {
        int rowl = wr * WM + i * 16 + quad * 4;
        #pragma unroll
        for (int r = 0; r < 4; ++r) {
          short v = f2bf((acc[i][j][r] + bias_v) * scl);
          if (isV) smem[coll * TP + rowl + r] = v;   // transposed for V
          else     smem[(rowl + r) * TP + coll] = v;
        }
      }
    }
    __syncthreads();
    const int b = m0 >> 11, s0 = m0 & (SEQ - 1);
    const int rseg = tid & 15, rrow = tid >> 4;
    if (!isV) {
      short* dst = (n0 < DMODEL) ? qb : kb;
      #pragma unroll
      for (int it = 0; it < 8; ++it) {
        int row = it * 16 + rrow;
        int colg = (n0 - nbase) + rseg * 8;
        int h = colg >> 6, d = colg & 63;
        s16x8 v = *(const s16x8*)&smem[row * TP + rseg * 8];
        *(s16x8*)(dst + ((b * NHEADS + h) * SEQ + s0 + row) * DHEAD + d) = v;
      }
    } else {
      #pragma unroll
      for (int it = 0; it < 8; ++it) {
        int drow = it * 16 + rrow;
        int colg = (n0 - nbase) + drow;
        int h = colg >> 6, d = colg & 63;
        s16x8 v = *(const s16x8*)&smem[drow * TP + rseg * 8];
        *(s16x8*)(vt + ((b * NHEADS + h) * DHEAD + d) * SEQ + s0 + rseg * 8) = v;
      }
    }
  } else {
    #pragma unroll
    for (int i = 0; i < TM; ++i)
      #pragma unroll
      for (int r = 0; r < 4; ++r) {
        int mrow = m0 + wr * WM + i * 16 + quad * 4 + r;
        #pragma unroll
        for (int j = 0; j < TN; ++j)
          out[mrow * DMODEL + n0 + wc * WN + j * 16 + l16] = acc[i][j][r];
      }
    (void)bq; (void)bk; (void)bv; (void)qb; (void)kb; (void)vt;
  }
}

// ================= flash attention v8 (unchanged from R9/R10) =================
// Split-2 T-halves (L2-served staging), 4 frags/wave, TWO chunks staged per
// barrier. Softmax: unnormalized exp2 per-lane (scale*log2e folded into Q);
// halves merge by pure addition in attn_merge.

__global__ __launch_bounds__(256, 2) void attn_k(
    const short* __restrict__ qbp, const short* __restrict__ kbp,
    const short* __restrict__ vtb, short* __restrict__ oP, float* __restrict__ lP)
{
  __shared__ short kls[2][8192];                    // 2 bufs x (2 chunks x 8KB)
  __shared__ short vls[2][8192];
  const int tid = threadIdx.x, wave = tid >> 6, lane = tid & 63;
  const int quad = lane >> 4, l16 = lane & 15;
  const int half = blockIdx.x & 1;
  const int bh = (blockIdx.x >> 1) & 31;
  const int qg = blockIdx.x >> 6;                   // 0..7, long (qg=0) first
  const int qt1 = qg * 8 + wave * 2;                // 0..62 even
  const int mF[4] = { qt1 * 16, (qt1 + 1) * 16, (126 - qt1) * 16, (127 - qt1) * 16 };
  const int nch = (127 - 8 * qg) / 4 + 1;          // block-uniform chunk count
  const short* Q  = qbp + bh * SEQ * DHEAD;
  const short* Kp = kbp + bh * SEQ * DHEAD;
  const short* Vt = vtb + bh * DHEAD * SEQ;

  bf16x8 qf[4][2];
  #pragma unroll
  for (int f = 0; f < 4; ++f) {
    qf[f][0] = *(const bf16x8*)&Q[(mF[f] + l16) * DHEAD + quad * 8];
    qf[f][1] = *(const bf16x8*)&Q[(mF[f] + l16) * DHEAD + 32 + quad * 8];
  }

  float lF[4] = {};
  f32x4 oF[4][4] = {};

  const int vdl = lane >> 3, vsl = lane & 7;        // V staging lane split

  auto stage1 = [&](int buf, int slot, int t0) {    // one 64-t chunk
    #pragma unroll
    for (int j = 0; j < 2; ++j) {
      int g = j * 4 + wave;                         // K ch-group 0..7
      const short* gp = Kp + (t0 + lane) * DHEAD + g * 8;
      __builtin_amdgcn_global_load_lds((__attribute__((address_space(1))) void*)gp,
                                       (__attribute__((address_space(3))) void*)&kls[buf][slot * 4096 + g * 512],
                                       16, 0, 0);
    }
    #pragma unroll
    for (int j = 0; j < 2; ++j) {
      int gd = j * 4 + wave;                        // V d-block 0..7
      const short* gp = Vt + (gd * 8 + vdl) * SEQ + t0 + ((vsl ^ vdl) * 8);
      __builtin_amdgcn_global_load_lds((__attribute__((address_space(1))) void*)gp,
                                       (__attribute__((address_space(3))) void*)&vls[buf][slot * 4096 + gd * 512],
                                       16, 0, 0);
    }
  };
  auto stagepair = [&](int buf, int cc) {           // chunks cc, cc+2 (owned set)
    stage1(buf, 0, cc * 64);
    if (cc + 2 < nch) stage1(buf, 1, (cc + 2) * 64);
  };

  stagepair(0, half);
  int it = 0;
  for (int cc = half; cc < nch; cc += 4, ++it) {
    __syncthreads();                                // drains stagepair; waves synced
    if (cc + 4 < nch) stagepair((it + 1) & 1, cc + 4);
    const int buf = it & 1;
    #pragma unroll
    for (int u = 0; u < 2; ++u) {                   // chunk within pair
      const int c = cc + 2 * u;
      if (c < nch) {                                // block-uniform
        const int t0 = c * 64;
        const int sb = u * 4096;
        #pragma unroll
        for (int t = 0; t < 4; ++t) {
          const int tb = t0 + t * 16;
          if (tb <= mF[3]) {                        // any fragment live (wave-uniform)
            bf16x8 kf0 = *(const bf16x8*)&kls[buf][sb + ((0 + quad) * 64 + t * 16 + l16) * 8];
            bf16x8 kf1 = *(const bf16x8*)&kls[buf][sb + ((4 + quad) * 64 + t * 16 + l16) * 8];
            s16x4 vf[4];
            {
              int gsw = ((t * 2 + (quad >> 1)) ^ (l16 & 7));
              #pragma unroll
              for (int dt = 0; dt < 4; ++dt)
                vf[dt] = *(const s16x4*)&vls[buf][sb + ((dt * 16 + l16) * 8 + gsw) * 8 + (quad & 1) * 4];
            }
            #pragma unroll
            for (int f = 0; f < 4; ++f) {
              if (tb <= mF[f]) {                    // wave-uniform
                f32x4 a = {};
                a = __builtin_amdgcn_mfma_f32_16x16x32_bf16(kf0, qf[f][0], a, 0, 0, 0);
                a = __builtin_amdgcn_mfma_f32_16x16x32_bf16(kf1, qf[f][1], a, 0, 0, 0);
                if (tb == mF[f]) {                  // diagonal: mask t > m
                  #pragma unroll
                  for (int r = 0; r < 4; ++r)
                    if (quad * 4 + r > l16) a[r] = -1e30f;
                }
                f32x4 p;
                #pragma unroll
                for (int r = 0; r < 4; ++r) p[r] = __builtin_amdgcn_exp2f(a[r]);
                lF[f] += (p[0] + p[1]) + (p[2] + p[3]);
                __hip_bfloat162 c01 = __float22bfloat162_rn(float2{p[0], p[1]});
                __hip_bfloat162 c23 = __float22bfloat162_rn(float2{p[2], p[3]});
                union { unsigned u2[2]; s16x4 s; } pu;
                pu.u2[0] = *(unsigned*)&c01; pu.u2[1] = *(unsigned*)&c23;
                #pragma unroll
                for (int dt = 0; dt < 4; ++dt)
                  oF[f][dt] = __builtin_amdgcn_mfma_f32_16x16x16bf16_1k(pu.s, vf[dt], oF[f][dt], 0, 0, 0);
              }
            }
          }
        }
      }
    }
  }

  // reduce l across quads; store partials [half][bh][s][64]
  float* lD = lP + (half * NBH + bh) * SEQ;
  short* oD = oP + ((half * NBH + bh) * SEQ) * DHEAD;
  #pragma unroll
  for (int f = 0; f < 4; ++f) {
    float l = lF[f];
    l += __shfl_xor(l, 16, 64); l += __shfl_xor(l, 32, 64);
    if (quad == 0) lD[mF[f] + l16] = l;
    #pragma unroll
    for (int r = 0; r < 4; ++r) {
      int s = mF[f] + quad * 4 + r;
      #pragma unroll
      for (int dt = 0; dt < 4; ++dt)
        oD[s * DHEAD + dt * 16 + l16] = f2bf(oF[f][dt][r]);
    }
  }
}

// ---------- merge halves: ob = (oE + oO) / (lE + lO), bf16 [b][s][h*64+d] ----
__global__ void attn_merge(const short* __restrict__ oP, const float* __restrict__ lP,
                           short* __restrict__ ob) {
  int idx = blockIdx.x * 256 + threadIdx.x;         // one thread = 8 outputs
  int d8 = idx & 7, s = (idx >> 3) & (SEQ - 1), bh = idx >> 14;
  s16x8 e = *(const s16x8*)&oP[((0   + bh) * SEQ + s) * DHEAD + d8 * 8];
  s16x8 o = *(const s16x8*)&oP[((NBH + bh) * SEQ + s) * DHEAD + d8 * 8];
  float linv = 1.0f / (lP[bh * SEQ + s] + lP[(NBH + bh) * SEQ + s]);
  s16x8 r;
  #pragma unroll
  for (int k = 0; k < 8; ++k) r[k] = f2bf((bf2f(e[k]) + bf2f(o[k])) * linv);
  int b = bh >> 4, h = bh & 15;
  *(s16x8*)&ob[(b * SEQ + s) * DMODEL + h * DHEAD + d8 * 8] = r;
}

extern "C" void kernel_launch(void* const* d_in, const int* in_sizes, int n_in,
                              void* d_out, int out_size, void* d_ws, size_t ws_size,
                              hipStream_t stream) {
  const float* x  = (const float*)d_in[0];
  const float* Wq = (const float*)d_in[1];
  const float* bq = (const float*)d_in[2];
  const float* Wk = (const float*)d_in[3];
  const float* bk = (const float*)d_in[4];
  const float* Wv = (const float*)d_in[5];
  const float* bv = (const float*)d_in[6];
  const float* Wo = (const float*)d_in[7];
  float* out = (float*)d_out;

  char* ws = (char*)d_ws;                         // ws is 256 MB (measured R7)
  short* xb  = (short*)(ws);                      // 8 MB  x bf16
  short* wtq = (short*)(ws + (8u  << 20));        // 6 MB  [Wq^T;Wk^T;Wv^T] bf16
  short* wto = (short*)(ws + (14u << 20));        // 2 MB  Wo^T bf16
  short* qb  = (short*)(ws + (16u << 20));        // 8 MB  Q (x 0.125*log2e folded)
  short* kb  = (short*)(ws + (24u << 20));        // 8 MB  K
  short* vt  = (short*)(ws + (32u << 20));        // 8 MB  V^T [bh][d][s]
  short* ob  = (short*)(ws + (40u << 20));        // 8 MB  attn out bf16
  short* oP  = (short*)(ws + (48u << 20));        // 16 MB o-partials [2][32][2048][64]
  float* lP  = (float*)(ws + (80u << 20));        // 0.5MB l-partials [2][32][2048]

  prep_fused<<<dim3(32, 32, 8), dim3(32, 8), 0, stream>>>(x, xb, Wq, Wk, Wv, Wo, wtq, wto);

  gemm_bf16<128, 128, 0><<<dim3(3 * DMODEL / 128, MROWS / 128), 256, 0, stream>>>(
      xb, wtq, bq, bk, bv, qb, kb, vt, nullptr);

  attn_k<<<8 * NBH * 2, 256, 0, stream>>>(qb, kb, vt, oP, lP);
  attn_merge<<<NBH * SEQ * 8 / 256, 256, 0, stream>>>(oP, lP, ob);

  gemm_bf16<64, 128, 1><<<dim3(DMODEL / 128, MROWS / 64), 256, 0, stream>>>(
      ob, wto, nullptr, nullptr, nullptr, nullptr, nullptr, nullptr, out);
}